// Round 5
// baseline (342.996 us; speedup 1.0000x reference)
//
#include <hip/hip_runtime.h>
#include <math.h>

constexpr int N = 100000;
constexpr int E = 1600000;
constexpr int C = 128;
constexpr int NPB   = 256;                       // nodes per bucket (pow2 -> shifts)
constexpr int NBUCK = (N + NPB - 1) / NPB;       // 391 buckets
constexpr int CAP   = 9472;                      // staging cap/bucket (mean 8192, +14 sigma)
constexpr int ADJ_STRIDE = CAP + NPB * 7;        // 11264: padded adj slots per bucket

typedef __attribute__((ext_vector_type(8))) short bf16x8;
typedef __attribute__((ext_vector_type(4))) float f32x4;

__device__ inline unsigned f2bf(float f) {   // fp32 -> bf16 bits, RNE
    unsigned u = __float_as_uint(f);
    return (u + 0x7fffu + ((u >> 16) & 1u)) >> 16;
}
__device__ inline unsigned pack2(float lo, float hi) {
    return f2bf(lo) | (f2bf(hi) << 16);
}
__device__ inline float bf_lo(unsigned m) { return __uint_as_float(m << 16); }
__device__ inline float bf_hi(unsigned m) { return __uint_as_float(m & 0xffff0000u); }

// ------------------------------------------------------------- bin pass ----
// Blocks 0..63 additionally perform the W split (absorbed k_wsplit):
// WhiT/WloT[c][k] = split-bf16 of W[k][c]; block 0 zeroes dummy z-row N.
__global__ __launch_bounds__(256) void k_bin(const int* __restrict__ ei,
                                             int* __restrict__ gcount,
                                             unsigned* __restrict__ staging,
                                             const float* __restrict__ W,
                                             unsigned short* __restrict__ WhiT,
                                             unsigned short* __restrict__ WloT,
                                             unsigned* __restrict__ z16) {
    const int t = threadIdx.x;
    if (blockIdx.x < 64) {
        const int i = blockIdx.x * 256 + t;      // i < 16384 = C*C
        const int k = i >> 7, c = i & 127;
        const float f = W[i];
        const unsigned hb = f2bf(f);
        WhiT[c * 128 + k] = (unsigned short)hb;
        WloT[c * 128 + k] = (unsigned short)f2bf(f - __uint_as_float(hb << 16));
        if (blockIdx.x == 0 && t < 64) z16[(size_t)N * 64 + t] = 0u;
    }
    __shared__ int cnt[NBUCK];
    __shared__ int wbase[NBUCK];
    const long tile = (long)blockIdx.x * 2048;
    for (int i = t; i < NBUCK; i += 256) cnt[i] = 0;
    __syncthreads();
    int b0[8], b1[8], lo0[8], lo1[8];
    unsigned p0[8], p1[8];
    bool val[8];
#pragma unroll
    for (int j = 0; j < 8; ++j) {
        long e = tile + j * 256 + t;
        val[j] = e < E;
        if (val[j]) {
            int u = __builtin_nontemporal_load(ei + e);
            int v = __builtin_nontemporal_load(ei + E + e);
            b0[j] = u >> 8;
            b1[j] = v >> 8;
            p0[j] = ((unsigned)(u & 255) << 17) | (unsigned)v;
            p1[j] = ((unsigned)(v & 255) << 17) | (unsigned)u;
            lo0[j] = atomicAdd(&cnt[b0[j]], 1);
            lo1[j] = atomicAdd(&cnt[b1[j]], 1);
        }
    }
    __syncthreads();
    for (int i = t; i < NBUCK; i += 256) wbase[i] = atomicAdd(&gcount[i], cnt[i]);
    __syncthreads();
#pragma unroll
    for (int j = 0; j < 8; ++j) {
        if (val[j]) {
            staging[(size_t)b0[j] * CAP + wbase[b0[j]] + lo0[j]] = p0[j];
            staging[(size_t)b1[j] * CAP + wbase[b1[j]] + lo1[j]] = p1[j];
        }
    }
}

// -------------------------------------------------- per-bucket CSR build ---
// Fixed per-bucket adj stride. Rows padded to x8 with dummy id N (zeroed
// z-row). Precise pad fill (only [d, pd) slots, <=7/node) -- no 17.6 MB
// prefill pass.
__global__ __launch_bounds__(512) void k_csr(const unsigned* __restrict__ staging,
                                             const int* __restrict__ gcount,
                                             int* __restrict__ deg,
                                             float* __restrict__ dinv,
                                             int* __restrict__ rowptr,
                                             int* __restrict__ adj) {
    __shared__ int hist[NPB];
    __shared__ int wpart[4];
    const int g = blockIdx.x;
    const int t = threadIdx.x;
    const int lane = t & 63, wid = t >> 6;
    const int cnt = gcount[g];
    int* slice = adj + (size_t)g * ADJ_STRIDE;
    for (int i = t; i < NPB; i += 512) hist[i] = 0;
    __syncthreads();
    const unsigned* base = staging + (size_t)g * CAP;
    for (int i = t; i < cnt; i += 512) atomicAdd(&hist[base[i] >> 17], 1);
    __syncthreads();
    const int d  = (t < NPB) ? hist[t] : 0;
    const int pd = (d + 7) & ~7;
    int v = pd;
#pragma unroll
    for (int off = 1; off < 64; off <<= 1) {
        int n = __shfl_up(v, off);
        if (lane >= off) v += n;
    }
    if (lane == 63 && wid < 4) wpart[wid] = v;
    __syncthreads();
    if (t == 0) {
        int r = 0;
#pragma unroll
        for (int w = 0; w < 4; ++w) { int x = wpart[w]; wpart[w] = r; r += x; }
    }
    __syncthreads();
    const int pstart = v - pd + ((wid < 4) ? wpart[wid] : 0);
    if (t < NPB) {
        const int node = g * NPB + t;
        if (node < N) {
            deg[node]    = d;
            dinv[node]   = rsqrtf((float)d + 1.0f);
            rowptr[node] = g * ADJ_STRIDE + pstart;
        }
        // precise pad fill: dummy id N in slots [d, pd)
        for (int i = d; i < pd; ++i) slice[pstart + i] = N;
    }
    __syncthreads();
    if (t < NPB) hist[t] = pstart;   // cursor for pass 2
    __syncthreads();
    for (int i = t; i < cnt; i += 512) {
        const unsigned e = base[i];
        const int pos = atomicAdd(&hist[e >> 17], 1);
        slice[pos] = (int)(e & 0x1ffffu);
    }
}

// ------------------------------------------------------------------ GEMM ---
// z16 = bf16(dinv * (x @ W)) via split-bf16 MFMA (16x16x32):
//   x = xh + xl, W = wh + wl; xw ~= xh*wh + xh*wl + xl*wh.
// Transposed-D trick: D[ch][node], each lane holds 4 consecutive channels.
__global__ __launch_bounds__(256) void k_gemm(const float* __restrict__ x,
                                              const unsigned short* __restrict__ WhiT,
                                              const unsigned short* __restrict__ WloT,
                                              const float* __restrict__ dinv,
                                              unsigned* __restrict__ z16) {
    __shared__ unsigned short xh[64][136];
    __shared__ unsigned short xl[64][136];
    const int t = threadIdx.x;
    const int bid = blockIdx.x;

#pragma unroll
    for (int j = 0; j < 8; ++j) {
        const int f4i = j * 256 + t;
        const int row = f4i >> 5;
        const int k4  = f4i & 31;
        const long gr = (long)bid * 64 + row;
        float4 f = {0.f, 0.f, 0.f, 0.f};
        if (gr < N) f = *(const float4*)(x + gr * C + k4 * 4);
        unsigned hq[4], lq[4];
#pragma unroll
        for (int e = 0; e < 4; ++e) {
            const float fe = (&f.x)[e];
            const unsigned hb = f2bf(fe);
            hq[e] = hb;
            lq[e] = f2bf(fe - __uint_as_float(hb << 16));
        }
        uint2 ph = {hq[0] | (hq[1] << 16), hq[2] | (hq[3] << 16)};
        uint2 pl = {lq[0] | (lq[1] << 16), lq[2] | (lq[3] << 16)};
        *(uint2*)(&xh[row][k4 * 4]) = ph;
        *(uint2*)(&xl[row][k4 * 4]) = pl;
    }
    __syncthreads();

    const int wid = t >> 6, l = t & 63;
    const int nb = wid * 16;
    const int lr = l & 15, lg = l >> 4;

    f32x4 acc[8];
#pragma unroll
    for (int i = 0; i < 8; ++i) acc[i] = (f32x4){0.f, 0.f, 0.f, 0.f};

    const unsigned short* xhp = &xh[nb + lr][lg * 8];
    const unsigned short* xlp = &xl[nb + lr][lg * 8];

#pragma unroll
    for (int kc = 0; kc < 4; ++kc) {
        const bf16x8 bh = *(const bf16x8*)(xhp + kc * 32);
        const bf16x8 bl = *(const bf16x8*)(xlp + kc * 32);
#pragma unroll
        for (int ct = 0; ct < 8; ++ct) {
            const int woff = (ct * 16 + lr) * 128 + kc * 32 + lg * 8;
            const bf16x8 ahi = *(const bf16x8*)(WhiT + woff);
            const bf16x8 alo = *(const bf16x8*)(WloT + woff);
            acc[ct] = __builtin_amdgcn_mfma_f32_16x16x32_bf16(ahi, bh, acc[ct], 0, 0, 0);
            acc[ct] = __builtin_amdgcn_mfma_f32_16x16x32_bf16(ahi, bl, acc[ct], 0, 0, 0);
            acc[ct] = __builtin_amdgcn_mfma_f32_16x16x32_bf16(alo, bh, acc[ct], 0, 0, 0);
        }
    }

    const long node = (long)bid * 64 + nb + lr;
    if (node < N) {
        const float dv = dinv[node];
#pragma unroll
        for (int ct = 0; ct < 8; ++ct) {
            const int ch0 = ct * 16 + lg * 4;
            uint2 pk = {pack2(dv * acc[ct][0], dv * acc[ct][1]),
                        pack2(dv * acc[ct][2], dv * acc[ct][3])};
            *(uint2*)(z16 + node * 64 + ch0 / 2) = pk;
        }
    }
}

// ---------------------------------------------------------------- gather ---
// One wave per node; lane owns channels 2*lane, 2*lane+1 (full 256 B rows).
// Launched as 3 node-range dispatches (profiling visibility; no numeric
// change). Two-bank pipeline, 16 row-loads in flight, scalar addressing.
__global__ __launch_bounds__(256) void k_gather(const int* __restrict__ rowptr,
                                                const int* __restrict__ deg,
                                                const float* __restrict__ dinv,
                                                const int* __restrict__ adj,
                                                const unsigned* __restrict__ z16,
                                                const float* __restrict__ b,
                                                float* __restrict__ out,
                                                int u0, int u1) {
    const int u = u0 + blockIdx.x * 4 + (threadIdx.x >> 6);
    if (u >= u1) return;
    const int lane = threadIdx.x & 63;
    const int d  = __builtin_amdgcn_readfirstlane(deg[u]);
    const int pd = (d + 7) & ~7;
    const int st = __builtin_amdgcn_readfirstlane(rowptr[u]);
    const float du = dinv[u];

    const unsigned ms = z16[((size_t)(unsigned)u << 6) + lane];
    float ax = bf_lo(ms), ay = bf_hi(ms);

    unsigned q0, q1, q2, q3, q4, q5, q6, q7;
    unsigned r0, r1, r2, r3, r4, r5, r6, r7;

#define ZR(j) z16[((size_t)(unsigned)__builtin_amdgcn_readlane(v, (j)) << 6) + lane]
#define LD8(A, p) A##0 = ZR((p) + 0); A##1 = ZR((p) + 1); A##2 = ZR((p) + 2); \
                  A##3 = ZR((p) + 3); A##4 = ZR((p) + 4); A##5 = ZR((p) + 5); \
                  A##6 = ZR((p) + 6); A##7 = ZR((p) + 7);
#define AC8(A) ax += bf_lo(A##0); ay += bf_hi(A##0); ax += bf_lo(A##1); ay += bf_hi(A##1); \
               ax += bf_lo(A##2); ay += bf_hi(A##2); ax += bf_lo(A##3); ay += bf_hi(A##3); \
               ax += bf_lo(A##4); ay += bf_hi(A##4); ax += bf_lo(A##5); ay += bf_hi(A##5); \
               ax += bf_lo(A##6); ay += bf_hi(A##6); ax += bf_lo(A##7); ay += bf_hi(A##7);

    for (int j0 = 0; j0 < pd; j0 += 64) {
        const int cntc = min(64, pd - j0);   // multiple of 8, wave-uniform
        const int v = adj[st + j0 + lane];   // lanes >= cntc: slack reads, unused
        int p = 8;
        LD8(q, 0);
        for (; p + 16 <= cntc; p += 16) {
            LD8(r, p); AC8(q);
            LD8(q, p + 8); AC8(r);
        }
        if (p < cntc) { LD8(r, p); AC8(q); AC8(r); }
        else          { AC8(q); }
    }
#undef ZR
#undef LD8
#undef AC8

    const float2 bb = *(const float2*)(b + 2 * lane);
    float2 o = {fmaf(du, ax, bb.x), fmaf(du, ay, bb.y)};
    *(float2*)(out + (size_t)u * C + 2 * lane) = o;
}

// ---------------------------------------------------------------- launch ---
extern "C" void kernel_launch(void* const* d_in, const int* in_sizes, int n_in,
                              void* d_out, int out_size, void* d_ws, size_t ws_size,
                              hipStream_t stream) {
    const float* x  = (const float*)d_in[0];
    const float* W  = (const float*)d_in[1];
    const float* b  = (const float*)d_in[2];
    const int*   ei = (const int*)d_in[3];
    float* out = (float*)d_out;

    // workspace: z16 [(N+1)*64 u32 = 25.6 MB, overlays staging 14.8 MB] |
    //            adj [NBUCK*ADJ_STRIDE + 64 slack] | deg | dinv | rowptr |
    //            gcount | WhiT | WloT
    char* p = (char*)d_ws;
    unsigned* z16 = (unsigned*)p;
    unsigned* staging = z16;                       // overlay (dead before gemm)
    p += (size_t)(N + 1) * 64 * sizeof(unsigned);
    int* adj = (int*)p;             p += ((size_t)NBUCK * ADJ_STRIDE + 64) * sizeof(int);
    int* deg = (int*)p;             p += (size_t)N * sizeof(int);
    float* dinv = (float*)p;        p += (size_t)N * sizeof(float);
    int* rowptr = (int*)p;          p += (size_t)(N + 4) * sizeof(int);
    int* gcount = (int*)p;          p += 512 * sizeof(int);
    unsigned short* WhiT = (unsigned short*)p;  p += (size_t)C * C * sizeof(unsigned short);
    unsigned short* WloT = (unsigned short*)p;

    hipMemsetAsync(gcount, 0, 512 * sizeof(int), stream);
    k_bin<<<(E + 2047) / 2048, 256, 0, stream>>>(ei, gcount, staging, W, WhiT, WloT, z16);
    k_csr<<<NBUCK, 512, 0, stream>>>(staging, gcount, deg, dinv, rowptr, adj);
    k_gemm<<<(N + 63) / 64, 256, 0, stream>>>(x, WhiT, WloT, dinv, z16);
    const int third = (N + 2) / 3;
    for (int s = 0; s < 3; ++s) {
        const int u0 = s * third;
        const int u1 = (u0 + third < N) ? (u0 + third) : N;
        k_gather<<<(u1 - u0 + 3) / 4, 256, 0, stream>>>(rowptr, deg, dinv, adj, z16, b, out, u0, u1);
    }
}

// Round 6
// 313.315 us; speedup vs baseline: 1.0947x; 1.0947x over previous
//
#include <hip/hip_runtime.h>
#include <math.h>

constexpr int N = 100000;
constexpr int E = 1600000;
constexpr int C = 128;
constexpr int NPB   = 256;                       // nodes per bucket (pow2 -> shifts)
constexpr int NBUCK = (N + NPB - 1) / NPB;       // 391 buckets
constexpr int CAP   = 9472;                      // staging cap/bucket (mean 8192, +14 sigma)
constexpr int ADJ_STRIDE = CAP + NPB * 7;        // 11264: padded adj slots per bucket
constexpr int NT = (N + 63) / 64;                // 1563 gemm tiles

typedef __attribute__((ext_vector_type(8))) short bf16x8;
typedef __attribute__((ext_vector_type(4))) float f32x4;

__device__ inline unsigned f2bf(float f) {   // fp32 -> bf16 bits, RNE
    unsigned u = __float_as_uint(f);
    return (u + 0x7fffu + ((u >> 16) & 1u)) >> 16;
}
__device__ inline unsigned pack2(float lo, float hi) {
    return f2bf(lo) | (f2bf(hi) << 16);
}
__device__ inline float bf_lo(unsigned m) { return __uint_as_float(m << 16); }
__device__ inline float bf_hi(unsigned m) { return __uint_as_float(m & 0xffff0000u); }

// ------------------------------------------------------------- bin pass ----
// Blocks 0..63 additionally split W into FRAGMENT-LINEAR bf16 hi/lo:
//   wfrag[(h*32 + ct*4 + kc)*512 + lane*8 + e] = split(W[k][c])
//   with c = ct*16 + (lane&15), k = kc*32 + (lane>>4)*8 + e.
// This is exactly the per-lane MFMA A-fragment order, so k_gemm stages it
// to LDS with a straight 64 KB copy and reads it conflict-free.
__global__ __launch_bounds__(256) void k_bin(const int* __restrict__ ei,
                                             int* __restrict__ gcount,
                                             unsigned* __restrict__ staging,
                                             const float* __restrict__ W,
                                             unsigned short* __restrict__ wfrag,
                                             unsigned* __restrict__ z16) {
    const int t = threadIdx.x;
    if (blockIdx.x < 64) {
        const int i = blockIdx.x * 256 + t;      // i < 16384 = C*C
        const int k = i >> 7, c = i & 127;
        const int ct = c >> 4, lr = c & 15;
        const int kc = k >> 5, lg = (k >> 3) & 3, e = k & 7;
        const int idx = ((ct * 4 + kc) * 64 + lg * 16 + lr) * 8 + e;
        const float f = W[i];
        const unsigned hb = f2bf(f);
        wfrag[idx]         = (unsigned short)hb;
        wfrag[16384 + idx] = (unsigned short)f2bf(f - __uint_as_float(hb << 16));
        if (blockIdx.x == 0 && t < 64) z16[(size_t)N * 64 + t] = 0u;
    }
    __shared__ int cnt[NBUCK];
    __shared__ int wbase[NBUCK];
    const long tile = (long)blockIdx.x * 2048;
    for (int i = t; i < NBUCK; i += 256) cnt[i] = 0;
    __syncthreads();
    int b0[8], b1[8], lo0[8], lo1[8];
    unsigned p0[8], p1[8];
    bool val[8];
#pragma unroll
    for (int j = 0; j < 8; ++j) {
        long e = tile + j * 256 + t;
        val[j] = e < E;
        if (val[j]) {
            int u = __builtin_nontemporal_load(ei + e);
            int v = __builtin_nontemporal_load(ei + E + e);
            b0[j] = u >> 8;
            b1[j] = v >> 8;
            p0[j] = ((unsigned)(u & 255) << 17) | (unsigned)v;
            p1[j] = ((unsigned)(v & 255) << 17) | (unsigned)u;
            lo0[j] = atomicAdd(&cnt[b0[j]], 1);
            lo1[j] = atomicAdd(&cnt[b1[j]], 1);
        }
    }
    __syncthreads();
    for (int i = t; i < NBUCK; i += 256) wbase[i] = atomicAdd(&gcount[i], cnt[i]);
    __syncthreads();
#pragma unroll
    for (int j = 0; j < 8; ++j) {
        if (val[j]) {
            staging[(size_t)b0[j] * CAP + wbase[b0[j]] + lo0[j]] = p0[j];
            staging[(size_t)b1[j] * CAP + wbase[b1[j]] + lo1[j]] = p1[j];
        }
    }
}

// -------------------------------------------------- per-bucket CSR build ---
__global__ __launch_bounds__(512) void k_csr(const unsigned* __restrict__ staging,
                                             const int* __restrict__ gcount,
                                             int* __restrict__ deg,
                                             float* __restrict__ dinv,
                                             int* __restrict__ rowptr,
                                             int* __restrict__ adj) {
    __shared__ int hist[NPB];
    __shared__ int wpart[4];
    const int g = blockIdx.x;
    const int t = threadIdx.x;
    const int lane = t & 63, wid = t >> 6;
    const int cnt = gcount[g];
    int* slice = adj + (size_t)g * ADJ_STRIDE;
    for (int i = t; i < NPB; i += 512) hist[i] = 0;
    __syncthreads();
    const unsigned* base = staging + (size_t)g * CAP;
    for (int i = t; i < cnt; i += 512) atomicAdd(&hist[base[i] >> 17], 1);
    __syncthreads();
    const int d  = (t < NPB) ? hist[t] : 0;
    const int pd = (d + 7) & ~7;
    int v = pd;
#pragma unroll
    for (int off = 1; off < 64; off <<= 1) {
        int n = __shfl_up(v, off);
        if (lane >= off) v += n;
    }
    if (lane == 63 && wid < 4) wpart[wid] = v;
    __syncthreads();
    if (t == 0) {
        int r = 0;
#pragma unroll
        for (int w = 0; w < 4; ++w) { int x = wpart[w]; wpart[w] = r; r += x; }
    }
    __syncthreads();
    const int pstart = v - pd + ((wid < 4) ? wpart[wid] : 0);
    if (t < NPB) {
        const int node = g * NPB + t;
        if (node < N) {
            deg[node]    = d;
            dinv[node]   = rsqrtf((float)d + 1.0f);
            rowptr[node] = g * ADJ_STRIDE + pstart;
        }
        for (int i = d; i < pd; ++i) slice[pstart + i] = N;   // precise pad fill
    }
    __syncthreads();
    if (t < NPB) hist[t] = pstart;   // cursor for pass 2
    __syncthreads();
    for (int i = t; i < cnt; i += 512) {
        const unsigned e = base[i];
        const int pos = atomicAdd(&hist[e >> 17], 1);
        slice[pos] = (int)(e & 0x1ffffu);
    }
}

// ------------------------------------------------------------------ GEMM ---
// z16 = bf16(dinv * (x @ W)) via split-bf16 MFMA, streaming form:
//  - W (hi+lo fragments, 64 KB) staged to LDS ONCE per block in fragment-
//    linear order -> all inner-loop W reads are conflict-free ds_read_b128.
//  - x read DIRECTLY from global into B-fragment layout (no x-LDS, no
//    barriers in the tile loop; waves fully independent).
//  - grid-stride over 64-node tiles amortizes the W staging.
__global__ __launch_bounds__(256) void k_gemm(const float* __restrict__ x,
                                              const unsigned short* __restrict__ wfrag,
                                              const float* __restrict__ dinv,
                                              unsigned* __restrict__ z16) {
    __shared__ unsigned short wlds[32768];   // 64 KB: [h][fid=ct*4+kc][lane][8]
    const int t = threadIdx.x;
    {
        const uint4* src = (const uint4*)wfrag;
        uint4* dst = (uint4*)wlds;
#pragma unroll
        for (int j = 0; j < 16; ++j) dst[t + 256 * j] = src[t + 256 * j];
    }
    __syncthreads();

    const int wid = t >> 6, l = t & 63;
    const int lr = l & 15, lg = l >> 4;
    const unsigned short* wl_hi = wlds + l * 8;           // + fid*512
    const unsigned short* wl_lo = wlds + 16384 + l * 8;

    for (int tile = blockIdx.x; tile < NT; tile += gridDim.x) {
        const long node = (long)tile * 64 + wid * 16 + lr;
        const bool nv = node < N;
        const float* xr = x + node * C + lg * 8;

        f32x4 acc[8];
#pragma unroll
        for (int i = 0; i < 8; ++i) acc[i] = (f32x4){0.f, 0.f, 0.f, 0.f};

#pragma unroll
        for (int kc = 0; kc < 4; ++kc) {
            float4 f0 = {0.f, 0.f, 0.f, 0.f}, f1 = {0.f, 0.f, 0.f, 0.f};
            if (nv) {
                f0 = *(const float4*)(xr + kc * 32);
                f1 = *(const float4*)(xr + kc * 32 + 4);
            }
            bf16x8 bh, bl;
#pragma unroll
            for (int e = 0; e < 8; ++e) {
                const float fe = (e < 4) ? (&f0.x)[e] : (&f1.x)[e - 4];
                const unsigned hb = f2bf(fe);
                bh[e] = (short)hb;
                bl[e] = (short)f2bf(fe - __uint_as_float(hb << 16));
            }
#pragma unroll
            for (int ct = 0; ct < 8; ++ct) {
                const int fo = (ct * 4 + kc) * 512;
                const bf16x8 ahi = *(const bf16x8*)(wl_hi + fo);
                const bf16x8 alo = *(const bf16x8*)(wl_lo + fo);
                acc[ct] = __builtin_amdgcn_mfma_f32_16x16x32_bf16(ahi, bh, acc[ct], 0, 0, 0);
                acc[ct] = __builtin_amdgcn_mfma_f32_16x16x32_bf16(ahi, bl, acc[ct], 0, 0, 0);
                acc[ct] = __builtin_amdgcn_mfma_f32_16x16x32_bf16(alo, bh, acc[ct], 0, 0, 0);
            }
        }

        if (nv) {
            const float dv = dinv[node];
#pragma unroll
            for (int ct = 0; ct < 8; ++ct) {
                uint2 pk = {pack2(dv * acc[ct][0], dv * acc[ct][1]),
                            pack2(dv * acc[ct][2], dv * acc[ct][3])};
                *(uint2*)(z16 + node * 64 + ct * 8 + lg * 2) = pk;
            }
        }
    }
}

// ---------------------------------------------------------------- gather ---
// One wave per node; lane owns channels 2*lane, 2*lane+1 (full 256 B rows).
// Launched as 3 node-range dispatches (profiling visibility). Two-bank
// pipeline, 16 row-loads in flight, scalar (readlane) addressing.
__global__ __launch_bounds__(256) void k_gather(const int* __restrict__ rowptr,
                                                const int* __restrict__ deg,
                                                const float* __restrict__ dinv,
                                                const int* __restrict__ adj,
                                                const unsigned* __restrict__ z16,
                                                const float* __restrict__ b,
                                                float* __restrict__ out,
                                                int u0, int u1) {
    const int u = u0 + blockIdx.x * 4 + (threadIdx.x >> 6);
    if (u >= u1) return;
    const int lane = threadIdx.x & 63;
    const int d  = __builtin_amdgcn_readfirstlane(deg[u]);
    const int pd = (d + 7) & ~7;
    const int st = __builtin_amdgcn_readfirstlane(rowptr[u]);
    const float du = dinv[u];

    const unsigned ms = z16[((size_t)(unsigned)u << 6) + lane];
    float ax = bf_lo(ms), ay = bf_hi(ms);

    unsigned q0, q1, q2, q3, q4, q5, q6, q7;
    unsigned r0, r1, r2, r3, r4, r5, r6, r7;

#define ZR(j) z16[((size_t)(unsigned)__builtin_amdgcn_readlane(v, (j)) << 6) + lane]
#define LD8(A, p) A##0 = ZR((p) + 0); A##1 = ZR((p) + 1); A##2 = ZR((p) + 2); \
                  A##3 = ZR((p) + 3); A##4 = ZR((p) + 4); A##5 = ZR((p) + 5); \
                  A##6 = ZR((p) + 6); A##7 = ZR((p) + 7);
#define AC8(A) ax += bf_lo(A##0); ay += bf_hi(A##0); ax += bf_lo(A##1); ay += bf_hi(A##1); \
               ax += bf_lo(A##2); ay += bf_hi(A##2); ax += bf_lo(A##3); ay += bf_hi(A##3); \
               ax += bf_lo(A##4); ay += bf_hi(A##4); ax += bf_lo(A##5); ay += bf_hi(A##5); \
               ax += bf_lo(A##6); ay += bf_hi(A##6); ax += bf_lo(A##7); ay += bf_hi(A##7);

    for (int j0 = 0; j0 < pd; j0 += 64) {
        const int cntc = min(64, pd - j0);   // multiple of 8, wave-uniform
        const int v = adj[st + j0 + lane];   // lanes >= cntc: slack reads, unused
        int p = 8;
        LD8(q, 0);
        for (; p + 16 <= cntc; p += 16) {
            LD8(r, p); AC8(q);
            LD8(q, p + 8); AC8(r);
        }
        if (p < cntc) { LD8(r, p); AC8(q); AC8(r); }
        else          { AC8(q); }
    }
#undef ZR
#undef LD8
#undef AC8

    const float2 bb = *(const float2*)(b + 2 * lane);
    float2 o = {fmaf(du, ax, bb.x), fmaf(du, ay, bb.y)};
    *(float2*)(out + (size_t)u * C + 2 * lane) = o;
}

// ---------------------------------------------------------------- launch ---
extern "C" void kernel_launch(void* const* d_in, const int* in_sizes, int n_in,
                              void* d_out, int out_size, void* d_ws, size_t ws_size,
                              hipStream_t stream) {
    const float* x  = (const float*)d_in[0];
    const float* W  = (const float*)d_in[1];
    const float* b  = (const float*)d_in[2];
    const int*   ei = (const int*)d_in[3];
    float* out = (float*)d_out;

    // workspace: z16 [(N+1)*64 u32 = 25.6 MB, overlays staging 14.8 MB] |
    //            adj [NBUCK*ADJ_STRIDE + 64 slack] | deg | dinv | rowptr |
    //            gcount | wfrag [32768 ushort = 64 KB, hi at 0, lo at 16384]
    char* p = (char*)d_ws;
    unsigned* z16 = (unsigned*)p;
    unsigned* staging = z16;                       // overlay (dead before gemm)
    p += (size_t)(N + 1) * 64 * sizeof(unsigned);
    int* adj = (int*)p;             p += ((size_t)NBUCK * ADJ_STRIDE + 64) * sizeof(int);
    int* deg = (int*)p;             p += (size_t)N * sizeof(int);
    float* dinv = (float*)p;        p += (size_t)N * sizeof(float);
    int* rowptr = (int*)p;          p += (size_t)(N + 4) * sizeof(int);
    int* gcount = (int*)p;          p += 512 * sizeof(int);
    unsigned short* wfrag = (unsigned short*)p;

    hipMemsetAsync(gcount, 0, 512 * sizeof(int), stream);
    k_bin<<<(E + 2047) / 2048, 256, 0, stream>>>(ei, gcount, staging, W, wfrag, z16);
    k_csr<<<NBUCK, 512, 0, stream>>>(staging, gcount, deg, dinv, rowptr, adj);
    k_gemm<<<512, 256, 0, stream>>>(x, wfrag, dinv, z16);
    const int third = (N + 2) / 3;
    for (int s = 0; s < 3; ++s) {
        const int u0 = s * third;
        const int u1 = (u0 + third < N) ? (u0 + third) : N;
        k_gather<<<(u1 - u0 + 3) / 4, 256, 0, stream>>>(rowptr, deg, dinv, adj, z16, b, out, u0, u1);
    }
}

// Round 7
// 304.160 us; speedup vs baseline: 1.1277x; 1.0301x over previous
//
#include <hip/hip_runtime.h>
#include <math.h>

constexpr int N = 100000;
constexpr int E = 1600000;
constexpr int C = 128;
constexpr int NPB   = 256;                       // nodes per bucket (pow2 -> shifts)
constexpr int NBUCK = (N + NPB - 1) / NPB;       // 391 buckets
constexpr int CAP   = 9472;                      // staging cap/bucket (mean 8192, +14 sigma)
constexpr int ADJ_STRIDE = CAP + NPB * 7;        // 11264: padded adj slots per bucket
constexpr int NT = (N + 63) / 64;                // 1563 gemm tiles
constexpr int GPAD = 16;                         // gcount stride: 1 counter per 64B line

typedef __attribute__((ext_vector_type(8))) short bf16x8;
typedef __attribute__((ext_vector_type(4))) float f32x4;

__device__ inline unsigned f2bf(float f) {   // fp32 -> bf16 bits, RNE
    unsigned u = __float_as_uint(f);
    return (u + 0x7fffu + ((u >> 16) & 1u)) >> 16;
}
__device__ inline unsigned pack2(float lo, float hi) {
    return f2bf(lo) | (f2bf(hi) << 16);
}
__device__ inline float bf_lo(unsigned m) { return __uint_as_float(m << 16); }
__device__ inline float bf_hi(unsigned m) { return __uint_as_float(m & 0xffff0000u); }

// ------------------------------------------------------------- bin pass ----
// count -> reserve -> re-read+scatter. 4096-edge tiles (391 blocks).
// Global atomics: 391 blocks x 391 buckets, ONE COUNTER PER 64B LINE
// (GPAD=16) -> ~391 atomics per line total, parallel across L2 banks
// (round-6 k_bin stalled 47us on 306K atomics crammed into 25 lines).
// Phase 2 re-reads the edge tile (L2-warm) so no per-edge register state;
// the reservation base is folded into the LDS counter, making phase-2's
// LDS atomicAdd return the absolute staging position.
// Blocks 0..63 additionally split W into fragment-linear bf16 hi/lo
// (wfrag[(h*32+ct*4+kc)*512 + lane*8 + e], the per-lane MFMA A-fragment
// order); block 0 zeroes dummy z-row N.
__global__ __launch_bounds__(256) void k_bin(const int* __restrict__ ei,
                                             int* __restrict__ gcount,
                                             unsigned* __restrict__ staging,
                                             const float* __restrict__ W,
                                             unsigned short* __restrict__ wfrag,
                                             unsigned* __restrict__ z16) {
    const int t = threadIdx.x;
    if (blockIdx.x < 64) {
        const int i = blockIdx.x * 256 + t;      // i < 16384 = C*C
        const int k = i >> 7, c = i & 127;
        const int ct = c >> 4, lr = c & 15;
        const int kc = k >> 5, lg = (k >> 3) & 3, e = k & 7;
        const int idx = ((ct * 4 + kc) * 64 + lg * 16 + lr) * 8 + e;
        const float f = W[i];
        const unsigned hb = f2bf(f);
        wfrag[idx]         = (unsigned short)hb;
        wfrag[16384 + idx] = (unsigned short)f2bf(f - __uint_as_float(hb << 16));
        if (blockIdx.x == 0 && t < 64) z16[(size_t)N * 64 + t] = 0u;
    }
    __shared__ int cnt[NBUCK];
    const long tile = (long)blockIdx.x * 4096;
    for (int i = t; i < NBUCK; i += 256) cnt[i] = 0;
    __syncthreads();
    // phase 1: count (no state kept)
#pragma unroll
    for (int j = 0; j < 16; ++j) {
        const long e = tile + j * 256 + t;
        if (e < E) {
            const int u = ei[e];
            const int v = ei[E + e];
            atomicAdd(&cnt[u >> 8], 1);
            atomicAdd(&cnt[v >> 8], 1);
        }
    }
    __syncthreads();
    // reserve: one padded global atomic per bucket; fold base into cnt
    for (int i = t; i < NBUCK; i += 256) {
        const int c = cnt[i];
        cnt[i] = atomicAdd(&gcount[i * GPAD], c);
    }
    __syncthreads();
    // phase 2: re-read (L2-warm) -> absolute position -> scatter
#pragma unroll
    for (int j = 0; j < 16; ++j) {
        const long e = tile + j * 256 + t;
        if (e < E) {
            const int u = ei[e];
            const int v = ei[E + e];
            const int bu = u >> 8, bv = v >> 8;
            const int pu = atomicAdd(&cnt[bu], 1);
            const int pv = atomicAdd(&cnt[bv], 1);
            staging[(size_t)bu * CAP + pu] = ((unsigned)(u & 255) << 17) | (unsigned)v;
            staging[(size_t)bv * CAP + pv] = ((unsigned)(v & 255) << 17) | (unsigned)u;
        }
    }
}

// -------------------------------------------------- per-bucket CSR build ---
__global__ __launch_bounds__(512) void k_csr(const unsigned* __restrict__ staging,
                                             const int* __restrict__ gcount,
                                             int* __restrict__ deg,
                                             float* __restrict__ dinv,
                                             int* __restrict__ rowptr,
                                             int* __restrict__ adj) {
    __shared__ int hist[NPB];
    __shared__ int wpart[4];
    const int g = blockIdx.x;
    const int t = threadIdx.x;
    const int lane = t & 63, wid = t >> 6;
    const int cnt = gcount[g * GPAD];
    int* slice = adj + (size_t)g * ADJ_STRIDE;
    for (int i = t; i < NPB; i += 512) hist[i] = 0;
    __syncthreads();
    const unsigned* base = staging + (size_t)g * CAP;
    for (int i = t; i < cnt; i += 512) atomicAdd(&hist[base[i] >> 17], 1);
    __syncthreads();
    const int d  = (t < NPB) ? hist[t] : 0;
    const int pd = (d + 7) & ~7;
    int v = pd;
#pragma unroll
    for (int off = 1; off < 64; off <<= 1) {
        int n = __shfl_up(v, off);
        if (lane >= off) v += n;
    }
    if (lane == 63 && wid < 4) wpart[wid] = v;
    __syncthreads();
    if (t == 0) {
        int r = 0;
#pragma unroll
        for (int w = 0; w < 4; ++w) { int x = wpart[w]; wpart[w] = r; r += x; }
    }
    __syncthreads();
    const int pstart = v - pd + ((wid < 4) ? wpart[wid] : 0);
    if (t < NPB) {
        const int node = g * NPB + t;
        if (node < N) {
            deg[node]    = d;
            dinv[node]   = rsqrtf((float)d + 1.0f);
            rowptr[node] = g * ADJ_STRIDE + pstart;
        }
        for (int i = d; i < pd; ++i) slice[pstart + i] = N;   // precise pad fill
    }
    __syncthreads();
    if (t < NPB) hist[t] = pstart;   // cursor for pass 2
    __syncthreads();
    for (int i = t; i < cnt; i += 512) {
        const unsigned e = base[i];
        const int pos = atomicAdd(&hist[e >> 17], 1);
        slice[pos] = (int)(e & 0x1ffffu);
    }
}

// ------------------------------------------------------------------ GEMM ---
// z16 = bf16(dinv * (x @ W)) via split-bf16 MFMA, streaming form: W in LDS
// fragment-linear (conflict-free ds_read_b128), x direct-from-global into
// B-fragment layout, no barriers in the tile loop, grid-stride tiles.
__global__ __launch_bounds__(256) void k_gemm(const float* __restrict__ x,
                                              const unsigned short* __restrict__ wfrag,
                                              const float* __restrict__ dinv,
                                              unsigned* __restrict__ z16) {
    __shared__ unsigned short wlds[32768];   // 64 KB: [h][fid=ct*4+kc][lane][8]
    const int t = threadIdx.x;
    {
        const uint4* src = (const uint4*)wfrag;
        uint4* dst = (uint4*)wlds;
#pragma unroll
        for (int j = 0; j < 16; ++j) dst[t + 256 * j] = src[t + 256 * j];
    }
    __syncthreads();

    const int wid = t >> 6, l = t & 63;
    const int lr = l & 15, lg = l >> 4;
    const unsigned short* wl_hi = wlds + l * 8;           // + fid*512
    const unsigned short* wl_lo = wlds + 16384 + l * 8;

    for (int tile = blockIdx.x; tile < NT; tile += gridDim.x) {
        const long node = (long)tile * 64 + wid * 16 + lr;
        const bool nv = node < N;
        const float* xr = x + node * C + lg * 8;

        f32x4 acc[8];
#pragma unroll
        for (int i = 0; i < 8; ++i) acc[i] = (f32x4){0.f, 0.f, 0.f, 0.f};

#pragma unroll
        for (int kc = 0; kc < 4; ++kc) {
            float4 f0 = {0.f, 0.f, 0.f, 0.f}, f1 = {0.f, 0.f, 0.f, 0.f};
            if (nv) {
                f0 = *(const float4*)(xr + kc * 32);
                f1 = *(const float4*)(xr + kc * 32 + 4);
            }
            bf16x8 bh, bl;
#pragma unroll
            for (int e = 0; e < 8; ++e) {
                const float fe = (e < 4) ? (&f0.x)[e] : (&f1.x)[e - 4];
                const unsigned hb = f2bf(fe);
                bh[e] = (short)hb;
                bl[e] = (short)f2bf(fe - __uint_as_float(hb << 16));
            }
#pragma unroll
            for (int ct = 0; ct < 8; ++ct) {
                const int fo = (ct * 4 + kc) * 512;
                const bf16x8 ahi = *(const bf16x8*)(wl_hi + fo);
                const bf16x8 alo = *(const bf16x8*)(wl_lo + fo);
                acc[ct] = __builtin_amdgcn_mfma_f32_16x16x32_bf16(ahi, bh, acc[ct], 0, 0, 0);
                acc[ct] = __builtin_amdgcn_mfma_f32_16x16x32_bf16(ahi, bl, acc[ct], 0, 0, 0);
                acc[ct] = __builtin_amdgcn_mfma_f32_16x16x32_bf16(alo, bh, acc[ct], 0, 0, 0);
            }
        }

        if (nv) {
            const float dv = dinv[node];
#pragma unroll
            for (int ct = 0; ct < 8; ++ct) {
                uint2 pk = {pack2(dv * acc[ct][0], dv * acc[ct][1]),
                            pack2(dv * acc[ct][2], dv * acc[ct][3])};
                *(uint2*)(z16 + node * 64 + ct * 8 + lg * 2) = pk;
            }
        }
    }
}

// ---------------------------------------------------------------- gather ---
// One wave per node; lane owns channels 2*lane, 2*lane+1 (full 256 B rows).
// 3 node-range dispatches (profiling visibility). Two-bank pipeline,
// 16 row-loads in flight, scalar (readlane) addressing.
__global__ __launch_bounds__(256) void k_gather(const int* __restrict__ rowptr,
                                                const int* __restrict__ deg,
                                                const float* __restrict__ dinv,
                                                const int* __restrict__ adj,
                                                const unsigned* __restrict__ z16,
                                                const float* __restrict__ b,
                                                float* __restrict__ out,
                                                int u0, int u1) {
    const int u = u0 + blockIdx.x * 4 + (threadIdx.x >> 6);
    if (u >= u1) return;
    const int lane = threadIdx.x & 63;
    const int d  = __builtin_amdgcn_readfirstlane(deg[u]);
    const int pd = (d + 7) & ~7;
    const int st = __builtin_amdgcn_readfirstlane(rowptr[u]);
    const float du = dinv[u];

    const unsigned ms = z16[((size_t)(unsigned)u << 6) + lane];
    float ax = bf_lo(ms), ay = bf_hi(ms);

    unsigned q0, q1, q2, q3, q4, q5, q6, q7;
    unsigned r0, r1, r2, r3, r4, r5, r6, r7;

#define ZR(j) z16[((size_t)(unsigned)__builtin_amdgcn_readlane(v, (j)) << 6) + lane]
#define LD8(A, p) A##0 = ZR((p) + 0); A##1 = ZR((p) + 1); A##2 = ZR((p) + 2); \
                  A##3 = ZR((p) + 3); A##4 = ZR((p) + 4); A##5 = ZR((p) + 5); \
                  A##6 = ZR((p) + 6); A##7 = ZR((p) + 7);
#define AC8(A) ax += bf_lo(A##0); ay += bf_hi(A##0); ax += bf_lo(A##1); ay += bf_hi(A##1); \
               ax += bf_lo(A##2); ay += bf_hi(A##2); ax += bf_lo(A##3); ay += bf_hi(A##3); \
               ax += bf_lo(A##4); ay += bf_hi(A##4); ax += bf_lo(A##5); ay += bf_hi(A##5); \
               ax += bf_lo(A##6); ay += bf_hi(A##6); ax += bf_lo(A##7); ay += bf_hi(A##7);

    for (int j0 = 0; j0 < pd; j0 += 64) {
        const int cntc = min(64, pd - j0);   // multiple of 8, wave-uniform
        const int v = adj[st + j0 + lane];   // lanes >= cntc: slack reads, unused
        int p = 8;
        LD8(q, 0);
        for (; p + 16 <= cntc; p += 16) {
            LD8(r, p); AC8(q);
            LD8(q, p + 8); AC8(r);
        }
        if (p < cntc) { LD8(r, p); AC8(q); AC8(r); }
        else          { AC8(q); }
    }
#undef ZR
#undef LD8
#undef AC8

    const float2 bb = *(const float2*)(b + 2 * lane);
    float2 o = {fmaf(du, ax, bb.x), fmaf(du, ay, bb.y)};
    *(float2*)(out + (size_t)u * C + 2 * lane) = o;
}

// ---------------------------------------------------------------- launch ---
extern "C" void kernel_launch(void* const* d_in, const int* in_sizes, int n_in,
                              void* d_out, int out_size, void* d_ws, size_t ws_size,
                              hipStream_t stream) {
    const float* x  = (const float*)d_in[0];
    const float* W  = (const float*)d_in[1];
    const float* b  = (const float*)d_in[2];
    const int*   ei = (const int*)d_in[3];
    float* out = (float*)d_out;

    // workspace: z16 [(N+1)*64 u32 = 25.6 MB, overlays staging 14.8 MB] |
    //            adj [NBUCK*ADJ_STRIDE + 64 slack] | deg | dinv | rowptr |
    //            gcount [NBUCK*GPAD ints, line-padded] | wfrag [64 KB]
    char* p = (char*)d_ws;
    unsigned* z16 = (unsigned*)p;
    unsigned* staging = z16;                       // overlay (dead before gemm)
    p += (size_t)(N + 1) * 64 * sizeof(unsigned);
    int* adj = (int*)p;             p += ((size_t)NBUCK * ADJ_STRIDE + 64) * sizeof(int);
    int* deg = (int*)p;             p += (size_t)N * sizeof(int);
    float* dinv = (float*)p;        p += (size_t)N * sizeof(float);
    int* rowptr = (int*)p;          p += (size_t)(N + 4) * sizeof(int);
    int* gcount = (int*)p;          p += (size_t)NBUCK * GPAD * sizeof(int);
    unsigned short* wfrag = (unsigned short*)p;

    hipMemsetAsync(gcount, 0, (size_t)NBUCK * GPAD * sizeof(int), stream);
    k_bin<<<(E + 4095) / 4096, 256, 0, stream>>>(ei, gcount, staging, W, wfrag, z16);
    k_csr<<<NBUCK, 512, 0, stream>>>(staging, gcount, deg, dinv, rowptr, adj);
    k_gemm<<<512, 256, 0, stream>>>(x, wfrag, dinv, z16);
    const int third = (N + 2) / 3;
    for (int s = 0; s < 3; ++s) {
        const int u0 = s * third;
        const int u1 = (u0 + third < N) ? (u0 + third) : N;
        k_gather<<<(u1 - u0 + 3) / 4, 256, 0, stream>>>(rowptr, deg, dinv, adj, z16, b, out, u0, u1);
    }
}